// Round 14
// baseline (121.472 us; speedup 1.0000x reference)
//
#include <hip/hip_runtime.h>
#include <math.h>

// RiemannianMetric: g[b,s,i,j] = sum_r tanh(x·W[r]+b[r])^2 A[r,i]A[r,j] + lam*I
// B=2 S=1024 DIM=256 RANK=32. Output 537 MB f32 -> store floor ~80us @6.7TB/s.
// R14: fuse R13's K1 dots INTO K2 (barrier-free): x staged in wave-private stage
// buf (wave_barrier only), 2 lanes/rank dots, w2=tanh^2 via shfl. K1 shrinks to a
// single-block ab16 builder (16KB). Fragments stay position-independent (L1-hot
// ab16) — avoids R11's 27us per-wave fragment-rebuild mistake. Store pipeline is
// R13's validated one: 8x{8 MFMA -> swizzled stage -> nt 512B-segment stores}.

constexpr int DIM = 256;

typedef float f32x4 __attribute__((ext_vector_type(4)));
typedef short s16x8 __attribute__((ext_vector_type(8))); // 8 bf16 = 4 VGPR

static __device__ __forceinline__ unsigned short f2bf(float f) {
    unsigned int u = __builtin_bit_cast(unsigned int, f);
    u = (u + 0x7FFFu + ((u >> 16) & 1u)) >> 16; // RNE
    return (unsigned short)u;
}
static __device__ __forceinline__ float bf2f(unsigned short s) {
    return __builtin_bit_cast(float, (unsigned int)s << 16);
}

// ---------------- Kernel 1: one-time A bf16 slabs (1 block, ~3us) ------------
// ab16[kg][j][e] = bf16(A[kg*8+e][j])
__global__ __launch_bounds__(256) void build_ab16_kernel(
    const float* __restrict__ A, unsigned short* __restrict__ ab16)
{
    const int tid = threadIdx.x;
    #pragma unroll
    for (int kg = 0; kg < 4; ++kg) {
        s16x8 pk;
        #pragma unroll
        for (int e = 0; e < 8; ++e)
            pk[e] = (short)f2bf(A[(kg * 8 + e) * DIM + tid]);
        *(s16x8*)&ab16[((size_t)kg * DIM + tid) * 8] = pk;
    }
}

// ---------------- Kernel 2: fused barrier-free G streamer --------------------
__global__ __launch_bounds__(256) void store_g_kernel(
    const float* __restrict__ x,             // [B*S, DIM]
    const unsigned short* __restrict__ ab16, // [4][256][8] plain A bf16
    const float* __restrict__ log_lambda,
    const float* __restrict__ W,             // [RANK, DIM]
    const float* __restrict__ bvec,          // [RANK]
    float* __restrict__ out)                 // [B*S, DIM, DIM]
{
    __shared__ alignas(16) float stage[4][16 * 128]; // 8KB per wave, 32KB total

    const int tid  = threadIdx.x;
    const int pos  = blockIdx.x;
    const int lane = tid & 63;
    const int rs   = tid >> 6;          // wave: rows 64rs..64rs+63
    const int kg   = lane >> 4, cl = lane & 15;

    float* sbuf = stage[rs];

    // ---- 1. wave-local x staging (1KB into this wave's stage buffer) --------
    *(f32x4*)&sbuf[lane * 4] = *(const f32x4*)(x + (size_t)pos * DIM + lane * 4);
    __builtin_amdgcn_wave_barrier();

    // ---- 2. tanh dots: rank r = lane>>1, half h = lane&1 (128 dims each) ----
    const int r = lane >> 1, h = lane & 1;
    const float* wrow = W + r * DIM + h * 128;
    const float* xrow = sbuf + h * 128;
    float dot = 0.f;
    #pragma unroll
    for (int d = 0; d < 128; d += 4) {
        f32x4 wv4 = *(const f32x4*)(wrow + d);
        f32x4 xv4 = *(const f32x4*)(xrow + d);
        dot = fmaf(wv4.x, xv4.x, dot);
        dot = fmaf(wv4.y, xv4.y, dot);
        dot = fmaf(wv4.z, xv4.z, dot);
        dot = fmaf(wv4.w, xv4.w, dot);
    }
    dot += __shfl_xor(dot, 1);
    const float wrt = tanhf(dot + bvec[r]);
    const float w2  = wrt * wrt;        // lanes {2r,2r+1} hold w2[r]
    __builtin_amdgcn_wave_barrier();    // x reads complete before stage reuse

    // ---- 3. distribute: w2v[e] = w2[kg*8+e] (src lane 16kg+2e) --------------
    float w2v[8];
    #pragma unroll
    for (int e = 0; e < 8; ++e)
        w2v[e] = __shfl(w2, 16 * kg + 2 * e);

    // ---- 4. afr: scaled row-tile frags from L1-hot ab16 (32 unpack-mul-cvt) -
    const unsigned short* abase = ab16 + (size_t)kg * DIM * 8;
    s16x8 afr[4];
    #pragma unroll
    for (int t = 0; t < 4; ++t) {
        s16x8 ar = *(const s16x8*)&abase[(size_t)((4 * rs + t) * 16 + cl) * 8];
        #pragma unroll
        for (int e = 0; e < 8; ++e)
            afr[t][e] = (short)f2bf(w2v[e] * bf2f((unsigned short)ar[e]));
    }

    const float lam = expf(log_lambda[0]);
    const bool on_diag_lane = (kg == (cl >> 2));
    const int  diag_slot    = cl & 3;

    const int wbase = cl * 128 + 4 * kg;   // stage write: row=cl, col=uu*16+4kg
    const int wswz  = (cl & 7) << 2;
    const int rrow0 = lane >> 5;           // stage read: 2 rows / instruction
    const int rcol  = (lane & 31) * 4;

    float* gbase = out + (size_t)pos * DIM * DIM;

    // ---- 5. main pipeline (R13-validated, byte-identical) -------------------
    #pragma unroll 1
    for (int t = 0; t < 4; ++t) {
        #pragma unroll 1
        for (int half = 0; half < 2; ++half) {
            s16x8 bfr[8]; // plain-A col-tile frags (L1-hot, no per-position work)
            #pragma unroll
            for (int uu = 0; uu < 8; ++uu) {
                const int u = half * 8 + uu;
                bfr[uu] = *(const s16x8*)&abase[(size_t)(u * 16 + cl) * 8];
            }
            #pragma unroll
            for (int uu = 0; uu < 8; ++uu) {
                const int u = half * 8 + uu;
                f32x4 acc = (f32x4)(0.f);
                acc = __builtin_amdgcn_mfma_f32_16x16x32_bf16(bfr[uu], afr[t], acc, 0, 0, 0);
                if (u == rs * 4 + t && on_diag_lane) // diagonal tile of G
                    acc[diag_slot] += lam;
                *(f32x4*)&sbuf[(wbase + uu * 16) ^ wswz] = acc;
            }
            #pragma unroll
            for (int m = 0; m < 8; ++m) {
                const int row = 2 * m + rrow0;
                f32x4 v = *(const f32x4*)&sbuf[(row * 128 + rcol) ^ ((row & 7) << 2)];
                float* gp = gbase + (size_t)(rs * 64 + t * 16 + row) * DIM
                                  + half * 128 + rcol;
                __builtin_nontemporal_store(v, (f32x4*)gp); // 512B contiguous segs
            }
        }
    }
}

// ---------------- Fallback monolith (R7-validated) ---------------------------
__global__ __launch_bounds__(256, 2) void riemannian_metric_fallback(
    const float* __restrict__ x, const float* __restrict__ A,
    const float* __restrict__ log_lambda, const float* __restrict__ W,
    const float* __restrict__ bvec, float* __restrict__ out)
{
    __shared__ float xs[DIM];
    __shared__ float sw[32];
    __shared__ alignas(16) unsigned short vt[4][DIM][8];
    __shared__ alignas(16) float stage[4][16 * 128];

    const int tid  = threadIdx.x;
    const int pos  = blockIdx.x;
    const int lane = tid & 63;
    const int rs   = tid >> 6;

    xs[tid] = x[(size_t)pos * DIM + tid];
    __syncthreads();
    {
        const int r = tid >> 3, seg = tid & 7;
        const f32x4* wr4 = (const f32x4*)(W + r * DIM + seg * 32);
        const f32x4* xr4 = (const f32x4*)(xs + seg * 32);
        float dot = 0.f;
        #pragma unroll
        for (int qq = 0; qq < 8; ++qq) {
            f32x4 wv = wr4[qq], xv = xr4[qq];
            dot = fmaf(wv.x, xv.x, dot);
            dot = fmaf(wv.y, xv.y, dot);
            dot = fmaf(wv.z, xv.z, dot);
            dot = fmaf(wv.w, xv.w, dot);
        }
        dot += __shfl_xor(dot, 1);
        dot += __shfl_xor(dot, 2);
        dot += __shfl_xor(dot, 4);
        if (seg == 0) sw[r] = tanhf(dot + bvec[r]);
    }
    __syncthreads();
    #pragma unroll
    for (int g = 0; g < 4; ++g) {
        s16x8 pk;
        #pragma unroll
        for (int e = 0; e < 8; ++e) {
            const int k = g * 8 + e;
            pk[e] = (short)f2bf(sw[k] * A[k * DIM + tid]);
        }
        *(s16x8*)&vt[g][tid][0] = pk;
    }
    __syncthreads();

    const int kg = lane >> 4, cl = lane & 15;
    s16x8 bfr[16];
    #pragma unroll
    for (int u = 0; u < 16; ++u)
        bfr[u] = *(const s16x8*)&vt[kg][u * 16 + cl][0];
    s16x8 afr[4];
    #pragma unroll
    for (int t = 0; t < 4; ++t)
        afr[t] = *(const s16x8*)&vt[kg][rs * 64 + t * 16 + cl][0];

    const float lam = expf(log_lambda[0]);
    const bool on_diag_lane = (kg == (cl >> 2));
    const int  diag_slot    = cl & 3;

    float* sbuf = stage[rs];
    const int wbase = cl * 128 + 4 * kg;
    const int wswz  = (cl & 7) << 2;
    const int rrow0 = lane >> 5;
    const int rcol  = (lane & 31) * 4;
    float* gbase = out + (size_t)pos * DIM * DIM;

    #pragma unroll 1
    for (int t = 0; t < 4; ++t) {
        #pragma unroll 1
        for (int half = 0; half < 2; ++half) {
            #pragma unroll
            for (int uu = 0; uu < 8; ++uu) {
                const int u = half * 8 + uu;
                f32x4 acc = (f32x4)(0.f);
                acc = __builtin_amdgcn_mfma_f32_16x16x32_bf16(bfr[u], afr[t], acc, 0, 0, 0);
                if (u == rs * 4 + t && on_diag_lane)
                    acc[diag_slot] += lam;
                *(f32x4*)&sbuf[(wbase + uu * 16) ^ wswz] = acc;
            }
            #pragma unroll
            for (int m = 0; m < 8; ++m) {
                const int row = 2 * m + rrow0;
                f32x4 v = *(const f32x4*)&sbuf[(row * 128 + rcol) ^ ((row & 7) << 2)];
                float* gp = gbase + (size_t)(rs * 64 + t * 16 + row) * DIM
                                  + half * 128 + rcol;
                __builtin_nontemporal_store(v, (f32x4*)gp);
            }
        }
    }
}

extern "C" void kernel_launch(void* const* d_in, const int* in_sizes, int n_in,
                              void* d_out, int out_size, void* d_ws, size_t ws_size,
                              hipStream_t stream) {
    const float* x          = (const float*)d_in[0];
    const float* A          = (const float*)d_in[1];
    const float* log_lambda = (const float*)d_in[2];
    const float* W          = (const float*)d_in[3];
    const float* bvec       = (const float*)d_in[4];
    float* out              = (float*)d_out;

    const int n_pos = in_sizes[0] / DIM; // B*S = 2048
    const size_t ab16_bytes = (size_t)4 * DIM * 8 * sizeof(unsigned short); // 16KB

    if (ws_size >= ab16_bytes) {
        unsigned short* ab16 = (unsigned short*)d_ws;
        build_ab16_kernel<<<1, 256, 0, stream>>>(A, ab16);
        store_g_kernel<<<n_pos, 256, 0, stream>>>(x, ab16, log_lambda, W, bvec, out);
    } else {
        riemannian_metric_fallback<<<n_pos, 256, 0, stream>>>(x, A, log_lambda, W, bvec, out);
    }
}